// Round 1
// baseline (1637.891 us; speedup 1.0000x reference)
//
#include <hip/hip_runtime.h>

#define BATCH   64
#define NCAPS   32
#define NROUTES 2048
#define INDIM   16
#define OUTDIM  32

// One block per (b, c). 1024 threads = 16 waves.
// Wave w owns nodes [w*128, (w+1)*128). Lane l: o = l&31, sub = l>>5.
// Lane holds priors p[j] = prior[n(j), o] with n(j) = w*128 + 2*j + sub.
__global__ __launch_bounds__(1024, 4) void caps_fused(
    const float* __restrict__ x,   // [B, N, I]
    const float* __restrict__ W,   // [C, N, I, O]
    float* __restrict__ out)       // [B, C, O]
{
    // XCD-friendly mapping: each XCD streams one W[c] at a time.
    int blk  = blockIdx.x;
    int xcd  = blk & 7;
    int rest = blk >> 3;
    int c = xcd * 4 + (rest >> 6);
    int b = rest & 63;

    int t   = threadIdx.x;
    int w   = t >> 6;
    int l   = t & 63;
    int o   = l & 31;
    int sub = l >> 5;

    __shared__ float Bsh[NROUTES];
    __shared__ float Psh[NROUTES];
    __shared__ float red[1024];
    __shared__ float spart[16][32];
    __shared__ float outArr[32];

    Bsh[t] = 0.0f;
    Bsh[t + 1024] = 0.0f;

    // ---- Priors ----
    float p[64];
    const int nodeBase = w * 128 + sub;
    const float* Wc = W + (size_t)c * NROUTES * (INDIM * OUTDIM);
    const float* xb = x + (size_t)b * NROUTES * INDIM;

    #pragma unroll 2
    for (int j = 0; j < 64; ++j) {
        int n = nodeBase + 2 * j;
        const float*  wp = Wc + (size_t)n * (INDIM * OUTDIM) + o;
        const float4* xp = (const float4*)(xb + n * INDIM);
        float4 x0 = xp[0], x1 = xp[1], x2 = xp[2], x3 = xp[3];
        float acc = 0.0f;
        acc += x0.x * wp[ 0*32]; acc += x0.y * wp[ 1*32];
        acc += x0.z * wp[ 2*32]; acc += x0.w * wp[ 3*32];
        acc += x1.x * wp[ 4*32]; acc += x1.y * wp[ 5*32];
        acc += x1.z * wp[ 6*32]; acc += x1.w * wp[ 7*32];
        acc += x2.x * wp[ 8*32]; acc += x2.y * wp[ 9*32];
        acc += x2.z * wp[10*32]; acc += x2.w * wp[11*32];
        acc += x3.x * wp[12*32]; acc += x3.y * wp[13*32];
        acc += x3.z * wp[14*32]; acc += x3.w * wp[15*32];
        p[j] = acc;
    }
    __syncthreads();

    // ---- Routing: 3 iterations ----
    for (int it = 0; it < 3; ++it) {
        // softmax over n: M = max(B), S = sum exp(B - M)
        float m = fmaxf(Bsh[t], Bsh[t + 1024]);
        red[t] = m;
        __syncthreads();
        for (int s = 512; s >= 1; s >>= 1) {
            if (t < s) red[t] = fmaxf(red[t], red[t + s]);
            __syncthreads();
        }
        float M = red[0];
        __syncthreads();

        float e0 = __expf(Bsh[t] - M);
        float e1 = __expf(Bsh[t + 1024] - M);
        Psh[t] = e0;
        Psh[t + 1024] = e1;
        red[t] = e0 + e1;
        __syncthreads();
        for (int s = 512; s >= 1; s >>= 1) {
            if (t < s) red[t] += red[t + s];
            __syncthreads();
        }
        float invS = 1.0f / red[0];
        __syncthreads();

        // s[o] = sum_n probs[n] * priors[n, o]
        float local = 0.0f;
        #pragma unroll 8
        for (int j = 0; j < 64; ++j) {
            local += Psh[nodeBase + 2 * j] * p[j];
        }
        local *= invS;
        local += __shfl_xor(local, 32, 64);   // combine sub halves
        if (l < 32) spart[w][l] = local;
        __syncthreads();

        // squash by first 32 threads (all in wave 0)
        if (t < 32) {
            float s = 0.0f;
            #pragma unroll
            for (int ww = 0; ww < 16; ++ww) s += spart[ww][t];
            float sq = s * s;
            sq += __shfl_xor(sq, 1, 64);
            sq += __shfl_xor(sq, 2, 64);
            sq += __shfl_xor(sq, 4, 64);
            sq += __shfl_xor(sq, 8, 64);
            sq += __shfl_xor(sq, 16, 64);
            float scale = sq / ((1.0f + sq) * sqrtf(sq));
            outArr[t] = s * scale;
        }
        __syncthreads();

        float outReg = outArr[o];

        // agreement: B[n] += sum_o priors[n,o] * outputs[o]  (skip on last iter)
        if (it < 2) {
            #pragma unroll 8
            for (int j = 0; j < 64; ++j) {
                float a = p[j] * outReg;
                a += __shfl_xor(a, 1, 64);
                a += __shfl_xor(a, 2, 64);
                a += __shfl_xor(a, 4, 64);
                a += __shfl_xor(a, 8, 64);
                a += __shfl_xor(a, 16, 64);
                if ((l & 31) == 0) Bsh[nodeBase + 2 * j] += a;
            }
            __syncthreads();
        }
    }

    if (t < 32) {
        out[((size_t)b * NCAPS + c) * OUTDIM + t] = outArr[t];
    }
}

extern "C" void kernel_launch(void* const* d_in, const int* in_sizes, int n_in,
                              void* d_out, int out_size, void* d_ws, size_t ws_size,
                              hipStream_t stream) {
    const float* x = (const float*)d_in[0];
    const float* W = (const float*)d_in[1];
    float* out = (float*)d_out;
    caps_fused<<<dim3(BATCH * NCAPS), dim3(1024), 0, stream>>>(x, W, out);
}

// Round 3
// 569.549 us; speedup vs baseline: 2.8758x; 2.8758x over previous
//
#include <hip/hip_runtime.h>
#include <hip/hip_fp16.h>

#define BATCH   64
#define NCAPS   32
#define NROUTES 2048
#define INDIM   16
#define OUTDIM  32

// ============================================================
// Kernel A: priors[b,c,n,o] = sum_i x[b,n,i] * W[c,n,i,o], stored fp16.
// Grid: 32 c * 256 tiles (8 nodes each). Block 256 = 4 waves.
// Wave handles a node PAIR: lanes 0-31 -> node n0 (b = lane), lanes 32-63 ->
// node n0+1 (b = lane-32). Each lane also carries b+32 in a second acc row.
// W loads are half-wave-uniform (broadcast); W is read exactly once from HBM.
// ============================================================
__global__ __launch_bounds__(256, 2) void caps_priors(
    const float* __restrict__ x,
    const float* __restrict__ W,
    unsigned short* __restrict__ pri)  // [B][C][N][O] fp16
{
    int bid  = blockIdx.x;
    int c    = bid >> 8;
    int tile = bid & 255;
    int t    = threadIdx.x;
    int wv   = t >> 6;
    int l    = t & 63;
    int bl   = l & 31;
    int nl   = tile * 8 + wv * 2 + (l >> 5);

    const float4* xp0 = (const float4*)(x + ((size_t)bl * NROUTES + nl) * INDIM);
    const float4* xp1 = (const float4*)(x + ((size_t)(bl + 32) * NROUTES + nl) * INDIM);
    const float4* wp  = (const float4*)(W + ((size_t)c * NROUTES + nl) * (INDIM * OUTDIM));

    float acc0[32], acc1[32];
    #pragma unroll
    for (int o = 0; o < 32; ++o) { acc0[o] = 0.f; acc1[o] = 0.f; }

    #pragma unroll
    for (int i4 = 0; i4 < 4; ++i4) {
        float4 xq0 = xp0[i4];
        float4 xq1 = xp1[i4];
        const float* xa = (const float*)&xq0;
        const float* xb = (const float*)&xq1;
        #pragma unroll
        for (int ii = 0; ii < 4; ++ii) {
            float a = xa[ii], b = xb[ii];
            #pragma unroll
            for (int o4 = 0; o4 < 8; ++o4) {
                float4 wq = wp[(i4 * 4 + ii) * 8 + o4];
                acc0[o4*4+0] += a * wq.x;  acc1[o4*4+0] += b * wq.x;
                acc0[o4*4+1] += a * wq.y;  acc1[o4*4+1] += b * wq.y;
                acc0[o4*4+2] += a * wq.z;  acc1[o4*4+2] += b * wq.z;
                acc0[o4*4+3] += a * wq.w;  acc1[o4*4+3] += b * wq.w;
            }
        }
    }

    uint4 st[4];
    unsigned* sp = (unsigned*)st;
    #pragma unroll
    for (int k = 0; k < 16; ++k) {
        unsigned lo = __half_as_ushort(__float2half_rn(acc0[2*k]));
        unsigned hi = __half_as_ushort(__float2half_rn(acc0[2*k+1]));
        sp[k] = lo | (hi << 16);
    }
    uint4* d0 = (uint4*)(pri + (((size_t)bl * NCAPS + c) * NROUTES + nl) * OUTDIM);
    d0[0] = st[0]; d0[1] = st[1]; d0[2] = st[2]; d0[3] = st[3];

    #pragma unroll
    for (int k = 0; k < 16; ++k) {
        unsigned lo = __half_as_ushort(__float2half_rn(acc1[2*k]));
        unsigned hi = __half_as_ushort(__float2half_rn(acc1[2*k+1]));
        sp[k] = lo | (hi << 16);
    }
    uint4* d1 = (uint4*)(pri + (((size_t)(bl + 32) * NCAPS + c) * NROUTES + nl) * OUTDIM);
    d1[0] = st[0]; d1[1] = st[1]; d1[2] = st[2]; d1[3] = st[3];
}

// ============================================================
// Kernel B: routing. One block (1024 thr, 16 waves) per (b,c).
// ROW layout: lane holds 2 full prior rows (nodes w*128+2l, +1), 32 o each.
// B-logits and agreement are lane-local; s[o] reduced by log-split transpose.
// Per-wave softmax max + exp-rescale merged at the wave-0 combine.
// ============================================================
__global__ __launch_bounds__(1024) void caps_route(
    const unsigned short* __restrict__ pri,
    float* __restrict__ out)
{
    int bid = blockIdx.x;
    int b = bid >> 5;
    int c = bid & 31;
    int t = threadIdx.x;
    int w = t >> 6;
    int l = t & 63;

    __shared__ float wmax[16];
    __shared__ float wsum[16];
    __shared__ float swave[16][32];
    __shared__ float outArr[32];

    int n0 = w * 128 + 2 * l;
    const uint4* pp = (const uint4*)(pri + (((size_t)b * NCAPS + c) * NROUTES + n0) * OUTDIM);
    uint4 q[8];
    #pragma unroll
    for (int k = 0; k < 8; ++k) q[k] = pp[k];

    float p0[32], p1[32];
    const unsigned* qu = (const unsigned*)q;
    #pragma unroll
    for (int k = 0; k < 16; ++k) {
        __half2 h0 = *(const __half2*)&qu[k];
        __half2 h1 = *(const __half2*)&qu[16 + k];
        float2 f0 = __half22float2(h0);
        float2 f1 = __half22float2(h1);
        p0[2*k]   = f0.x;
        p0[2*k+1] = f0.y;
        p1[2*k]   = f1.x;
        p1[2*k+1] = f1.y;
    }

    float B0 = 0.f, B1 = 0.f;

    for (int it = 0; it < 3; ++it) {
        // per-wave max + sum (stability handled by rescale at combine)
        float m = fmaxf(B0, B1);
        #pragma unroll
        for (int mk = 1; mk < 64; mk <<= 1) m = fmaxf(m, __shfl_xor(m, mk, 64));
        float e0 = __expf(B0 - m);
        float e1 = __expf(B1 - m);
        float sm = e0 + e1;
        #pragma unroll
        for (int mk = 1; mk < 64; mk <<= 1) sm += __shfl_xor(sm, mk, 64);
        if (l == 0) { wmax[w] = m; wsum[w] = sm; }

        // s_loc[o] = e0*p0[o] + e1*p1[o]
        float s[32];
        #pragma unroll
        for (int o = 0; o < 32; ++o) s[o] = e0 * p0[o] + e1 * p1[o];

        // log-split transpose-reduce across 64 lanes (31+1 swizzles)
        #pragma unroll
        for (int step = 0; step < 5; ++step) {
            const int mk = 1 << step;
            const int half = 16 >> step;
            bool bit = (l & mk) != 0;
            #pragma unroll
            for (int k = 0; k < half; ++k) {
                float keep = bit ? s[k + half] : s[k];
                float send = bit ? s[k] : s[k + half];
                s[k] = keep + __shfl_xor(send, mk, 64);
            }
        }
        s[0] += __shfl_xor(s[0], 32, 64);
        int orev = __brev(l & 31) >> 27;   // 5-bit reverse: lane -> o
        if (l < 32) swave[w][orev] = s[0];
        __syncthreads();

        if (t < 32) {
            float M = wmax[0];
            #pragma unroll
            for (int k = 1; k < 16; ++k) M = fmaxf(M, wmax[k]);
            float S = 0.f, sv = 0.f;
            #pragma unroll
            for (int k = 0; k < 16; ++k) {
                float sc = __expf(wmax[k] - M);
                S  += wsum[k] * sc;
                sv += swave[k][t] * sc;
            }
            sv /= S;
            float sq = sv * sv;
            sq += __shfl_xor(sq, 1, 64);
            sq += __shfl_xor(sq, 2, 64);
            sq += __shfl_xor(sq, 4, 64);
            sq += __shfl_xor(sq, 8, 64);
            sq += __shfl_xor(sq, 16, 64);
            float scale = sq / ((1.f + sq) * sqrtf(sq));
            float ov = sv * scale;
            if (it == 2) out[((size_t)b * NCAPS + c) * OUTDIM + t] = ov;
            else         outArr[t] = ov;
        }

        if (it < 2) {
            __syncthreads();
            float o32[32];
            const float4* oa = (const float4*)outArr;
            #pragma unroll
            for (int k = 0; k < 8; ++k) {
                float4 v = oa[k];
                o32[4*k] = v.x; o32[4*k+1] = v.y; o32[4*k+2] = v.z; o32[4*k+3] = v.w;
            }
            float d0a=0,d0b=0,d0c=0,d0d=0, d1a=0,d1b=0,d1c=0,d1d=0;
            #pragma unroll
            for (int k = 0; k < 8; ++k) {
                d0a += p0[4*k]  *o32[4*k];   d0b += p0[4*k+1]*o32[4*k+1];
                d0c += p0[4*k+2]*o32[4*k+2]; d0d += p0[4*k+3]*o32[4*k+3];
                d1a += p1[4*k]  *o32[4*k];   d1b += p1[4*k+1]*o32[4*k+1];
                d1c += p1[4*k+2]*o32[4*k+2]; d1d += p1[4*k+3]*o32[4*k+3];
            }
            B0 += (d0a + d0b) + (d0c + d0d);
            B1 += (d1a + d1b) + (d1c + d1d);
        }
    }
}

// ============================================================
// Fallback (round-1 fused kernel) if ws is too small for priors.
// ============================================================
__global__ __launch_bounds__(1024, 4) void caps_fused(
    const float* __restrict__ x,
    const float* __restrict__ W,
    float* __restrict__ out)
{
    int blk  = blockIdx.x;
    int xcd  = blk & 7;
    int rest = blk >> 3;
    int c = xcd * 4 + (rest >> 6);
    int b = rest & 63;

    int t   = threadIdx.x;
    int w   = t >> 6;
    int l   = t & 63;
    int o   = l & 31;
    int sub = l >> 5;

    __shared__ float Bsh[NROUTES];
    __shared__ float Psh[NROUTES];
    __shared__ float red[1024];
    __shared__ float spart[16][32];
    __shared__ float outArr[32];

    Bsh[t] = 0.0f;
    Bsh[t + 1024] = 0.0f;

    float p[64];
    const int nodeBase = w * 128 + sub;
    const float* Wc = W + (size_t)c * NROUTES * (INDIM * OUTDIM);
    const float* xb = x + (size_t)b * NROUTES * INDIM;

    #pragma unroll 2
    for (int j = 0; j < 64; ++j) {
        int n = nodeBase + 2 * j;
        const float*  wp = Wc + (size_t)n * (INDIM * OUTDIM) + o;
        const float4* xp = (const float4*)(xb + n * INDIM);
        float4 x0 = xp[0], x1 = xp[1], x2 = xp[2], x3 = xp[3];
        float acc = 0.0f;
        acc += x0.x * wp[ 0*32]; acc += x0.y * wp[ 1*32];
        acc += x0.z * wp[ 2*32]; acc += x0.w * wp[ 3*32];
        acc += x1.x * wp[ 4*32]; acc += x1.y * wp[ 5*32];
        acc += x1.z * wp[ 6*32]; acc += x1.w * wp[ 7*32];
        acc += x2.x * wp[ 8*32]; acc += x2.y * wp[ 9*32];
        acc += x2.z * wp[10*32]; acc += x2.w * wp[11*32];
        acc += x3.x * wp[12*32]; acc += x3.y * wp[13*32];
        acc += x3.z * wp[14*32]; acc += x3.w * wp[15*32];
        p[j] = acc;
    }
    __syncthreads();

    for (int it = 0; it < 3; ++it) {
        float m = fmaxf(Bsh[t], Bsh[t + 1024]);
        red[t] = m;
        __syncthreads();
        for (int s = 512; s >= 1; s >>= 1) {
            if (t < s) red[t] = fmaxf(red[t], red[t + s]);
            __syncthreads();
        }
        float M = red[0];
        __syncthreads();

        float e0 = __expf(Bsh[t] - M);
        float e1 = __expf(Bsh[t + 1024] - M);
        Psh[t] = e0;
        Psh[t + 1024] = e1;
        red[t] = e0 + e1;
        __syncthreads();
        for (int s = 512; s >= 1; s >>= 1) {
            if (t < s) red[t] += red[t + s];
            __syncthreads();
        }
        float invS = 1.0f / red[0];
        __syncthreads();

        float local = 0.0f;
        #pragma unroll 8
        for (int j = 0; j < 64; ++j) local += Psh[nodeBase + 2 * j] * p[j];
        local *= invS;
        local += __shfl_xor(local, 32, 64);
        if (l < 32) spart[w][l] = local;
        __syncthreads();

        if (t < 32) {
            float s = 0.0f;
            #pragma unroll
            for (int ww = 0; ww < 16; ++ww) s += spart[ww][t];
            float sq = s * s;
            sq += __shfl_xor(sq, 1, 64);
            sq += __shfl_xor(sq, 2, 64);
            sq += __shfl_xor(sq, 4, 64);
            sq += __shfl_xor(sq, 8, 64);
            sq += __shfl_xor(sq, 16, 64);
            float scale = sq / ((1.0f + sq) * sqrtf(sq));
            outArr[t] = s * scale;
        }
        __syncthreads();

        float outReg = outArr[o];
        if (it < 2) {
            #pragma unroll 8
            for (int j = 0; j < 64; ++j) {
                float a = p[j] * outReg;
                a += __shfl_xor(a, 1, 64);
                a += __shfl_xor(a, 2, 64);
                a += __shfl_xor(a, 4, 64);
                a += __shfl_xor(a, 8, 64);
                a += __shfl_xor(a, 16, 64);
                if ((l & 31) == 0) Bsh[nodeBase + 2 * j] += a;
            }
            __syncthreads();
        }
    }

    if (t < 32) out[((size_t)b * NCAPS + c) * OUTDIM + t] = outArr[t];
}

extern "C" void kernel_launch(void* const* d_in, const int* in_sizes, int n_in,
                              void* d_out, int out_size, void* d_ws, size_t ws_size,
                              hipStream_t stream) {
    const float* x = (const float*)d_in[0];
    const float* W = (const float*)d_in[1];
    float* out = (float*)d_out;

    const size_t need = (size_t)BATCH * NCAPS * NROUTES * OUTDIM * 2;  // 256 MiB fp16
    if (ws_size >= need) {
        caps_priors<<<dim3(NCAPS * 256), dim3(256), 0, stream>>>(x, W, (unsigned short*)d_ws);
        caps_route<<<dim3(BATCH * NCAPS), dim3(1024), 0, stream>>>((const unsigned short*)d_ws, out);
    } else {
        caps_fused<<<dim3(BATCH * NCAPS), dim3(1024), 0, stream>>>(x, W, out);
    }
}